// Round 7
// baseline (403.237 us; speedup 1.0000x reference)
//
#include <hip/hip_runtime.h>

// LinearShift: out = round_to_fixed(x) @ v.T + round_to_fixed(bias)
// v = 2^round(shift) * (-1)^(round(sign)%2), shift in [-10,-1], sign in [-1,0]
// x_q is integer*2^-8 with |int| < 2048 -> EXACT in fp16. Weights ±2^k exact in fp16.
// => f16 MFMA GEMM (fp32 accum) is numerically exact up to fp32 accumulation.

typedef _Float16 half8 __attribute__((ext_vector_type(8)));
typedef _Float16 half4v __attribute__((ext_vector_type(4)));
typedef float floatx4 __attribute__((ext_vector_type(4)));

__device__ __forceinline__ float qfix(float x) {
    // floor(x*256 + 0.5), clip to [-32768, 32767], * 2^-8
    // (x*256 is exact in f32, so mul+add == fma here; matches jnp bit-for-bit)
    float r = floorf(x * 256.0f + 0.5f);
    r = fminf(fmaxf(r, -32768.0f), 32767.0f);
    return r * 0.00390625f;
}

__global__ __launch_bounds__(256) void quantize_x_kernel(
        const float* __restrict__ x, _Float16* __restrict__ xq, int n4) {
    int i = blockIdx.x * 256 + threadIdx.x;
    const int stride = gridDim.x * 256;
    for (; i < n4; i += stride) {
        float4 v = reinterpret_cast<const float4*>(x)[i];
        half4v o;
        o[0] = (_Float16)qfix(v.x);
        o[1] = (_Float16)qfix(v.y);
        o[2] = (_Float16)qfix(v.z);
        o[3] = (_Float16)qfix(v.w);
        reinterpret_cast<half4v*>(xq)[i] = o;
    }
}

__global__ __launch_bounds__(256) void make_v_kernel(
        const float* __restrict__ shift, const float* __restrict__ sign,
        _Float16* __restrict__ v, int n4) {
    int i = blockIdx.x * 256 + threadIdx.x;
    const int stride = gridDim.x * 256;
    for (; i < n4; i += stride) {
        float4 sh = reinterpret_cast<const float4*>(shift)[i];
        float4 sg = reinterpret_cast<const float4*>(sign)[i];
        half4v o;
        // jnp.round = half-to-even = rintf (default rounding mode).
        // Python (-1.0)%2==1 -> negative; (-0.0)%2==0 -> positive.
        o[0] = (_Float16)ldexpf((rintf(sg.x) == 0.0f) ? 1.0f : -1.0f, (int)rintf(sh.x));
        o[1] = (_Float16)ldexpf((rintf(sg.y) == 0.0f) ? 1.0f : -1.0f, (int)rintf(sh.y));
        o[2] = (_Float16)ldexpf((rintf(sg.z) == 0.0f) ? 1.0f : -1.0f, (int)rintf(sh.z));
        o[3] = (_Float16)ldexpf((rintf(sg.w) == 0.0f) ? 1.0f : -1.0f, (int)rintf(sh.w));
        reinterpret_cast<half4v*>(v)[i] = o;
    }
}

#define BM 128
#define BN 128
#define BK 32

__device__ __forceinline__ void async_load16(const void* g, void* l) {
    __builtin_amdgcn_global_load_lds(
        (const __attribute__((address_space(1))) unsigned int*)g,
        (__attribute__((address_space(3))) unsigned int*)l,
        16, 0, 0);
}

// NT GEMM: A is MxK row-major (xq), B is NxK row-major (v), C = A*B^T + bias_q
// m97 structure: 128x128 tile, BK=32, 4 waves (2x2), each wave 64x64 (4x4 frags),
// global_load_lds width-16 staging, 2 barriers per K-step.
__global__ __launch_bounds__(256) void gemm_kernel(
        const _Float16* __restrict__ A,   // M x K
        const _Float16* __restrict__ B,   // N x K
        const float* __restrict__ bias,   // N
        float* __restrict__ C,            // M x N
        int M, int N, int K) {
    __shared__ _Float16 sA[BM * BK];
    __shared__ _Float16 sB[BN * BK];
    const int t = threadIdx.x;
    const int lane = t & 63;
    const int wave = t >> 6;
    const int wr = wave >> 1, wc = wave & 1;
    const int bm = blockIdx.y * BM;
    const int bn = blockIdx.x * BN;

    const int srow = t >> 2;          // staging row within 64-row chunk
    const int scol = (t & 3) * 8;     // staging col (elements)

    const int fr = lane & 15;         // fragment row
    const int fk = (lane >> 4) * 8;   // fragment k-offset

    floatx4 acc[4][4] = {};

    for (int k0 = 0; k0 < K; k0 += BK) {
        __syncthreads();
        #pragma unroll
        for (int i = 0; i < 2; ++i) {
            const _Float16* gA = A + (size_t)(bm + i * 64 + srow) * K + (k0 + scol);
            const _Float16* gB = B + (size_t)(bn + i * 64 + srow) * K + (k0 + scol);
            async_load16(gA, sA + i * 2048 + t * 8);
            async_load16(gB, sB + i * 2048 + t * 8);
        }
        __syncthreads();

        half8 af[4], bf[4];
        #pragma unroll
        for (int m = 0; m < 4; ++m)
            af[m] = *reinterpret_cast<const half8*>(sA + (wr * 64 + m * 16 + fr) * BK + fk);
        #pragma unroll
        for (int n = 0; n < 4; ++n)
            bf[n] = *reinterpret_cast<const half8*>(sB + (wc * 64 + n * 16 + fr) * BK + fk);

        #pragma unroll
        for (int m = 0; m < 4; ++m)
            #pragma unroll
            for (int n = 0; n < 4; ++n)
                acc[m][n] = __builtin_amdgcn_mfma_f32_16x16x32_f16(
                    af[m], bf[n], acc[m][n], 0, 0, 0);
    }

    // Epilogue: C/D layout col=lane&15, row=(lane>>4)*4+reg (m89-verified)
    const int crow = (lane >> 4) * 4;
    const int ccol = lane & 15;
    #pragma unroll
    for (int n = 0; n < 4; ++n) {
        const int gcol = bn + wc * 64 + n * 16 + ccol;
        const float bq = qfix(bias[gcol]);
        #pragma unroll
        for (int m = 0; m < 4; ++m) {
            const int grow = bm + wr * 64 + m * 16 + crow;
            float* p = C + (size_t)grow * N + gcol;
            #pragma unroll
            for (int r = 0; r < 4; ++r)
                p[(size_t)r * N] = acc[m][n][r] + bq;
        }
    }
}

extern "C" void kernel_launch(void* const* d_in, const int* in_sizes, int n_in,
                              void* d_out, int out_size, void* d_ws, size_t ws_size,
                              hipStream_t stream) {
    const float* x     = (const float*)d_in[0];
    const float* shift = (const float*)d_in[1];
    const float* sign  = (const float*)d_in[2];
    const float* bias  = (const float*)d_in[3];
    float* out = (float*)d_out;

    const int N = in_sizes[3];            // 4096 (OUT)
    const int K = in_sizes[1] / N;        // 4096 (IN)
    const int M = in_sizes[0] / K;        // 8192

    _Float16* xq = (_Float16*)d_ws;
    _Float16* v  = (_Float16*)((char*)d_ws + (size_t)M * K * sizeof(_Float16));

    quantize_x_kernel<<<2048, 256, 0, stream>>>(x, xq, M * K / 4);
    make_v_kernel<<<2048, 256, 0, stream>>>(shift, sign, v, N * K / 4);

    dim3 grid(N / BN, M / BM);
    gemm_kernel<<<grid, 256, 0, stream>>>(xq, v, bias, out, M, N, K);
}

// Round 10
// 311.796 us; speedup vs baseline: 1.2933x; 1.2933x over previous
//
#include <hip/hip_runtime.h>

// LinearShift: out = round_to_fixed(x) @ v.T + round_to_fixed(bias)
// x_q = int*2^-8 (|int|<2048, fp16-exact); v = ±2^k, k in [-10,-1] (fp16-exact)
// => f16 MFMA GEMM, fp32 accum: validated absmax 0.0 in round 7.
//
// GEMM: 256x256 tile, BK=64, 512 thr (8 waves 2x4), 4-phase/K-tile schedule,
// counted vmcnt(4) in steady state. ROUND 9 FIX: last K-tile has no staging,
// so steady-state vmcnt(4) no-ops left {B1,A1}@cur in flight while P2/P3 read
// them (absmax 10.2 in round 8). Last-tile P1 now drains vmcnt(0).

typedef _Float16 half8 __attribute__((ext_vector_type(8)));
typedef _Float16 half4v __attribute__((ext_vector_type(4)));
typedef float floatx4 __attribute__((ext_vector_type(4)));

__device__ __forceinline__ float qfix(float x) {
    float r = floorf(x * 256.0f + 0.5f);
    r = fminf(fmaxf(r, -32768.0f), 32767.0f);
    return r * 0.00390625f;
}

__global__ __launch_bounds__(256) void quantize_x_kernel(
        const float* __restrict__ x, _Float16* __restrict__ xq, int n4) {
    int i = blockIdx.x * 256 + threadIdx.x;
    const int stride = gridDim.x * 256;
    for (; i < n4; i += stride) {
        float4 v = reinterpret_cast<const float4*>(x)[i];
        half4v o;
        o[0] = (_Float16)qfix(v.x);
        o[1] = (_Float16)qfix(v.y);
        o[2] = (_Float16)qfix(v.z);
        o[3] = (_Float16)qfix(v.w);
        reinterpret_cast<half4v*>(xq)[i] = o;
    }
}

__global__ __launch_bounds__(256) void make_v_kernel(
        const float* __restrict__ shift, const float* __restrict__ sign,
        _Float16* __restrict__ v, int n4) {
    int i = blockIdx.x * 256 + threadIdx.x;
    const int stride = gridDim.x * 256;
    for (; i < n4; i += stride) {
        float4 sh = reinterpret_cast<const float4*>(shift)[i];
        float4 sg = reinterpret_cast<const float4*>(sign)[i];
        half4v o;
        o[0] = (_Float16)ldexpf((rintf(sg.x) == 0.0f) ? 1.0f : -1.0f, (int)rintf(sh.x));
        o[1] = (_Float16)ldexpf((rintf(sg.y) == 0.0f) ? 1.0f : -1.0f, (int)rintf(sh.y));
        o[2] = (_Float16)ldexpf((rintf(sg.z) == 0.0f) ? 1.0f : -1.0f, (int)rintf(sh.z));
        o[3] = (_Float16)ldexpf((rintf(sg.w) == 0.0f) ? 1.0f : -1.0f, (int)rintf(sh.w));
        reinterpret_cast<half4v*>(v)[i] = o;
    }
}

__device__ __forceinline__ void async_load16(const void* g, void* l) {
    __builtin_amdgcn_global_load_lds(
        (const __attribute__((address_space(1))) unsigned int*)g,
        (__attribute__((address_space(3))) unsigned int*)l,
        16, 0, 0);
}

// Stage one half-tile (128 rows x 64 f16 = 16KB) with XOR-swizzled source:
// LDS (linear in t) position (r, blk) holds G[row0+r][k0 + (blk^(r&7))*8].
__device__ __forceinline__ void stage_half(const _Float16* __restrict__ G, int ldg,
                                           int row0, int k0, _Float16* lds_half, int t) {
    #pragma unroll
    for (int l = 0; l < 2; ++l) {
        const int r  = l * 64 + (t >> 3);
        const int cb = (t & 7) ^ (r & 7);
        async_load16(G + (size_t)(row0 + r) * ldg + (k0 + cb * 8),
                     lds_half + l * 4096 + t * 8);
    }
}

// Swizzled fragment read: undoes the write-side XOR. Row stride 64 f16 = 128B;
// blk = (ks*4+fko)^(r&7) spreads 16 rows over 8 bank-slots -> 2-way (free).
__device__ __forceinline__ half8 read_frag(const _Float16* hb, int r, int ks, int fko) {
    const int blk = (ks * 4 + fko) ^ (r & 7);
    return *reinterpret_cast<const half8*>(hb + r * 64 + blk * 8);
}

#define MFMA_QUAD(ACCQ)                                                   \
    _Pragma("unroll")                                                     \
    for (int mf = 0; mf < 4; ++mf)                                        \
      _Pragma("unroll")                                                   \
      for (int nf = 0; nf < 2; ++nf)                                      \
        _Pragma("unroll")                                                 \
        for (int ks = 0; ks < 2; ++ks)                                    \
          ACCQ[mf][nf] = __builtin_amdgcn_mfma_f32_16x16x32_f16(          \
              af[mf][ks], bf[nf][ks], ACCQ[mf][nf], 0, 0, 0);

// barrier; lgkmcnt(0); sched_barrier (rule #18); setprio-wrapped 16 MFMA.
#define PHASE_CORE(ACCQ)                                                  \
    asm volatile("" ::: "memory");                                        \
    __builtin_amdgcn_s_barrier();                                         \
    asm volatile("s_waitcnt lgkmcnt(0)" ::: "memory");                    \
    __builtin_amdgcn_sched_barrier(0);                                    \
    __builtin_amdgcn_s_setprio(1);                                        \
    MFMA_QUAD(ACCQ);                                                      \
    __builtin_amdgcn_s_setprio(0);

#define END_BARRIER()                                                     \
    asm volatile("" ::: "memory");                                        \
    __builtin_amdgcn_s_barrier();

#define READ_AF(HALF)                                                     \
    _Pragma("unroll")                                                     \
    for (int mf = 0; mf < 4; ++mf)                                        \
      _Pragma("unroll")                                                   \
      for (int ks = 0; ks < 2; ++ks)                                      \
        af[mf][ks] = read_frag((HALF), wrow * 64 + mf * 16 + fr, ks, fko);

#define READ_BF(HALF)                                                     \
    _Pragma("unroll")                                                     \
    for (int nf = 0; nf < 2; ++nf)                                        \
      _Pragma("unroll")                                                   \
      for (int ks = 0; ks < 2; ++ks)                                      \
        bf[nf][ks] = read_frag((HALF), wcol * 32 + nf * 16 + fr, ks, fko);

// LDS (dynamic, 128KB): [slot(2)][A0,A1,B0,B1][128][64] f16, 8192 f16/half.
__global__ __launch_bounds__(512, 2) void gemm8_kernel(
        const _Float16* __restrict__ A,   // M x K
        const _Float16* __restrict__ B,   // N x K
        const float* __restrict__ bias,   // N
        float* __restrict__ C,            // M x N
        int M, int N, int K) {
    extern __shared__ _Float16 smem[];
    const int t = threadIdx.x;
    const int lane = t & 63;
    const int w = t >> 6;
    const int wrow = w >> 2;   // 0..1
    const int wcol = w & 3;    // 0..3
    const int fr  = lane & 15;
    const int fko = lane >> 4; // 0..3

    // T1: bijective XCD swizzle (nwg % 8 == 0 for this shape)
    const int nwg = gridDim.x;
    const int bid = blockIdx.x;
    const int cpx = nwg >> 3;
    const int swz = (bid & 7) * cpx + (bid >> 3);
    const int ntN = N >> 8;
    const int bm = (swz / ntN) << 8;
    const int bn = (swz % ntN) << 8;

    // prologue: stage K-tile 0 into slot 0, drain once
    stage_half(A, K, bm,       0, smem,         t);
    stage_half(B, K, bn,       0, smem + 16384, t);
    stage_half(B, K, bn + 128, 0, smem + 24576, t);
    stage_half(A, K, bm + 128, 0, smem + 8192,  t);
    asm volatile("s_waitcnt vmcnt(0)" ::: "memory");
    __builtin_amdgcn_s_barrier();

    floatx4 acc[2][2][4][2] = {};   // [qm][qn][mf][nf] — all static-indexed
    const int NT = K >> 6;

    // Steady-state invariant entering tile kt: 4 loads outstanding
    // ({B1,A1}@cur staged by P3/P4 of tile kt-1). P1/P2's vmcnt(4) retire
    // {B1}@cur / {A1}@cur only because each phase first pushes outstanding
    // to 6. Last tile stages nothing -> P1 must drain vmcnt(0) instead.
    for (int kt = 0; kt < NT; ++kt) {
        const int cur = kt & 1;
        _Float16* cb = smem + cur * 32768;
        _Float16* nb = smem + (cur ^ 1) * 32768;
        const _Float16* cA0 = cb;
        const _Float16* cA1 = cb + 8192;
        const _Float16* cB0 = cb + 16384;
        const _Float16* cB1 = cb + 24576;
        const int k1 = (kt + 1) << 6;
        const bool more = (kt + 1 < NT);

        half8 af[4][2], bf[2][2];

        // Phase 1: quadrant (0,0). A0,B0 guaranteed by prev P4's vmcnt+barrier.
        READ_AF(cA0);
        READ_BF(cB0);
        if (more) stage_half(A, K, bm, k1, nb, t);             // A0'
        PHASE_CORE(acc[0][0]);
        if (more) { asm volatile("s_waitcnt vmcnt(4)" ::: "memory"); }  // retires B1@cur
        else      { asm volatile("s_waitcnt vmcnt(0)" ::: "memory"); }  // drain {B1,A1}@cur
        END_BARRIER();

        // Phase 2: quadrant (0,1). New B1 (reuse af).
        READ_BF(cB1);
        if (more) stage_half(B, K, bn, k1, nb + 16384, t);     // B0'
        PHASE_CORE(acc[0][1]);
        if (more) { asm volatile("s_waitcnt vmcnt(4)" ::: "memory"); }  // retires A1@cur
        END_BARRIER();

        // Phase 3: quadrant (1,1). New A1 (reuse bf=B1). No wait needed.
        READ_AF(cA1);
        if (more) stage_half(B, K, bn + 128, k1, nb + 24576, t); // B1'
        PHASE_CORE(acc[1][1]);
        END_BARRIER();

        // Phase 4: quadrant (1,0). Re-read B0 (landed long ago). vmcnt(4)
        // retires {A0',B0'} so next tile's P1 reads are safe after barrier.
        READ_BF(cB0);
        if (more) stage_half(A, K, bm + 128, k1, nb + 8192, t);  // A1'
        PHASE_CORE(acc[1][0]);
        if (more) { asm volatile("s_waitcnt vmcnt(4)" ::: "memory"); }
        END_BARRIER();
    }

    // Epilogue: C/D layout col=lane&15, row=(lane>>4)*4+reg (validated round 7)
    #pragma unroll
    for (int qm = 0; qm < 2; ++qm)
      #pragma unroll
      for (int qn = 0; qn < 2; ++qn)
        #pragma unroll
        for (int nf = 0; nf < 2; ++nf) {
            const int gcol = bn + qn * 128 + wcol * 32 + nf * 16 + (lane & 15);
            const float bq = qfix(bias[gcol]);
            #pragma unroll
            for (int mf = 0; mf < 4; ++mf) {
                const int grow = bm + qm * 128 + wrow * 64 + mf * 16 + ((lane >> 4) << 2);
                float* p = C + (size_t)grow * N + gcol;
                #pragma unroll
                for (int r = 0; r < 4; ++r)
                    p[(size_t)r * N] = acc[qm][qn][mf][nf][r] + bq;
            }
        }
}

extern "C" void kernel_launch(void* const* d_in, const int* in_sizes, int n_in,
                              void* d_out, int out_size, void* d_ws, size_t ws_size,
                              hipStream_t stream) {
    const float* x     = (const float*)d_in[0];
    const float* shift = (const float*)d_in[1];
    const float* sign  = (const float*)d_in[2];
    const float* bias  = (const float*)d_in[3];
    float* out = (float*)d_out;

    const int N = in_sizes[3];            // 4096
    const int K = in_sizes[1] / N;        // 4096
    const int M = in_sizes[0] / K;        // 8192

    _Float16* xq = (_Float16*)d_ws;
    _Float16* v  = (_Float16*)((char*)d_ws + (size_t)M * K * sizeof(_Float16));

    quantize_x_kernel<<<2048, 256, 0, stream>>>(x, xq, M * K / 4);
    make_v_kernel<<<2048, 256, 0, stream>>>(shift, sign, v, N * K / 4);

    (void)hipFuncSetAttribute(reinterpret_cast<const void*>(gemm8_kernel),
                              hipFuncAttributeMaxDynamicSharedMemorySize, 131072);
    const int nblk = (M / 256) * (N / 256);
    gemm8_kernel<<<nblk, 512, 131072, stream>>>(xq, v, bias, out, M, N, K);
}

// Round 11
// 309.846 us; speedup vs baseline: 1.3014x; 1.0063x over previous
//
#include <hip/hip_runtime.h>

// LinearShift: out = round_to_fixed(x) @ v.T + round_to_fixed(bias)
// x_q = int*2^-8 (|int|<2048, fp16-exact); v = ±2^k, k in [-10,-1] (fp16-exact)
// => f16 MFMA GEMM, fp32 accum: absmax 0.0 validated (rounds 7, 10).
//
// 256x256 tile, BK=64, 512 thr (8 waves 2x4), 4-phase/K-tile, counted vmcnt(4),
// T1 XCD swizzle + T2 XOR swizzle (bank-conflict 0 measured) + T5 setprio.
// ROUND 11: (a) retain bf0+bf1 register sets -> P4 has zero ds_reads
// (28->24 b128/K-tile); (b) drop explicit lgkmcnt(0)+sched_barrier pin --
// reads are plain HIP loads, so compiler emits fine-grained lgkmcnt(N)
// per-MFMA (m97-verified) instead of a full drain before the cluster.

typedef _Float16 half8 __attribute__((ext_vector_type(8)));
typedef _Float16 half4v __attribute__((ext_vector_type(4)));
typedef float floatx4 __attribute__((ext_vector_type(4)));

__device__ __forceinline__ float qfix(float x) {
    float r = floorf(x * 256.0f + 0.5f);
    r = fminf(fmaxf(r, -32768.0f), 32767.0f);
    return r * 0.00390625f;
}

__global__ __launch_bounds__(256) void quantize_x_kernel(
        const float* __restrict__ x, _Float16* __restrict__ xq, int n4) {
    int i = blockIdx.x * 256 + threadIdx.x;
    const int stride = gridDim.x * 256;
    for (; i < n4; i += stride) {
        float4 v = reinterpret_cast<const float4*>(x)[i];
        half4v o;
        o[0] = (_Float16)qfix(v.x);
        o[1] = (_Float16)qfix(v.y);
        o[2] = (_Float16)qfix(v.z);
        o[3] = (_Float16)qfix(v.w);
        reinterpret_cast<half4v*>(xq)[i] = o;
    }
}

__global__ __launch_bounds__(256) void make_v_kernel(
        const float* __restrict__ shift, const float* __restrict__ sign,
        _Float16* __restrict__ v, int n4) {
    int i = blockIdx.x * 256 + threadIdx.x;
    const int stride = gridDim.x * 256;
    for (; i < n4; i += stride) {
        float4 sh = reinterpret_cast<const float4*>(shift)[i];
        float4 sg = reinterpret_cast<const float4*>(sign)[i];
        half4v o;
        o[0] = (_Float16)ldexpf((rintf(sg.x) == 0.0f) ? 1.0f : -1.0f, (int)rintf(sh.x));
        o[1] = (_Float16)ldexpf((rintf(sg.y) == 0.0f) ? 1.0f : -1.0f, (int)rintf(sh.y));
        o[2] = (_Float16)ldexpf((rintf(sg.z) == 0.0f) ? 1.0f : -1.0f, (int)rintf(sh.z));
        o[3] = (_Float16)ldexpf((rintf(sg.w) == 0.0f) ? 1.0f : -1.0f, (int)rintf(sh.w));
        reinterpret_cast<half4v*>(v)[i] = o;
    }
}

__device__ __forceinline__ void async_load16(const void* g, void* l) {
    __builtin_amdgcn_global_load_lds(
        (const __attribute__((address_space(1))) unsigned int*)g,
        (__attribute__((address_space(3))) unsigned int*)l,
        16, 0, 0);
}

// Stage one half-tile (128 rows x 64 f16 = 16KB) with XOR-swizzled source:
// LDS (linear in t) position (r, blk) holds G[row0+r][k0 + (blk^(r&7))*8].
__device__ __forceinline__ void stage_half(const _Float16* __restrict__ G, int ldg,
                                           int row0, int k0, _Float16* lds_half, int t) {
    #pragma unroll
    for (int l = 0; l < 2; ++l) {
        const int r  = l * 64 + (t >> 3);
        const int cb = (t & 7) ^ (r & 7);
        async_load16(G + (size_t)(row0 + r) * ldg + (k0 + cb * 8),
                     lds_half + l * 4096 + t * 8);
    }
}

// Swizzled fragment read: undoes the write-side XOR. Row stride 64 f16 = 128B;
// blk = (ks*4+fko)^(r&7) spreads 16 rows over 8 bank-slots -> 2-way (free).
__device__ __forceinline__ half8 read_frag(const _Float16* hb, int r, int ks, int fko) {
    const int blk = (ks * 4 + fko) ^ (r & 7);
    return *reinterpret_cast<const half8*>(hb + r * 64 + blk * 8);
}

#define MFMA_QUAD(ACCQ, BF)                                               \
    _Pragma("unroll")                                                     \
    for (int mf = 0; mf < 4; ++mf)                                        \
      _Pragma("unroll")                                                   \
      for (int nf = 0; nf < 2; ++nf)                                      \
        _Pragma("unroll")                                                 \
        for (int ks = 0; ks < 2; ++ks)                                    \
          ACCQ[mf][nf] = __builtin_amdgcn_mfma_f32_16x16x32_f16(          \
              af[mf][ks], BF[nf][ks], ACCQ[mf][nf], 0, 0, 0);

// Leading barrier + setprio-wrapped MFMA cluster. NO explicit lgkmcnt drain:
// reads are plain loads, compiler emits per-MFMA lgkmcnt(N) (m97 pattern).
#define PHASE_CORE(ACCQ, BF)                                              \
    asm volatile("" ::: "memory");                                        \
    __builtin_amdgcn_s_barrier();                                         \
    __builtin_amdgcn_s_setprio(1);                                        \
    MFMA_QUAD(ACCQ, BF);                                                  \
    __builtin_amdgcn_s_setprio(0);

#define END_BARRIER()                                                     \
    asm volatile("" ::: "memory");                                        \
    __builtin_amdgcn_s_barrier();

#define READ_AF(HALF)                                                     \
    _Pragma("unroll")                                                     \
    for (int mf = 0; mf < 4; ++mf)                                        \
      _Pragma("unroll")                                                   \
      for (int ks = 0; ks < 2; ++ks)                                      \
        af[mf][ks] = read_frag((HALF), wrow * 64 + mf * 16 + fr, ks, fko);

#define READ_BF(DST, HALF)                                                \
    _Pragma("unroll")                                                     \
    for (int nf = 0; nf < 2; ++nf)                                        \
      _Pragma("unroll")                                                   \
      for (int ks = 0; ks < 2; ++ks)                                      \
        DST[nf][ks] = read_frag((HALF), wcol * 32 + nf * 16 + fr, ks, fko);

// LDS (dynamic, 128KB): [slot(2)][A0,A1,B0,B1][128][64] f16, 8192 f16/half.
__global__ __launch_bounds__(512, 2) void gemm8_kernel(
        const _Float16* __restrict__ A,   // M x K
        const _Float16* __restrict__ B,   // N x K
        const float* __restrict__ bias,   // N
        float* __restrict__ C,            // M x N
        int M, int N, int K) {
    extern __shared__ _Float16 smem[];
    const int t = threadIdx.x;
    const int lane = t & 63;
    const int w = t >> 6;
    const int wrow = w >> 2;   // 0..1
    const int wcol = w & 3;    // 0..3
    const int fr  = lane & 15;
    const int fko = lane >> 4; // 0..3

    // T1: bijective XCD swizzle (nwg % 8 == 0 for this shape)
    const int nwg = gridDim.x;
    const int bid = blockIdx.x;
    const int cpx = nwg >> 3;
    const int swz = (bid & 7) * cpx + (bid >> 3);
    const int ntN = N >> 8;
    const int bm = (swz / ntN) << 8;
    const int bn = (swz % ntN) << 8;

    // prologue: stage K-tile 0 into slot 0, drain once
    stage_half(A, K, bm,       0, smem,         t);
    stage_half(B, K, bn,       0, smem + 16384, t);
    stage_half(B, K, bn + 128, 0, smem + 24576, t);
    stage_half(A, K, bm + 128, 0, smem + 8192,  t);
    asm volatile("s_waitcnt vmcnt(0)" ::: "memory");
    __builtin_amdgcn_s_barrier();

    floatx4 acc[2][2][4][2] = {};   // [qm][qn][mf][nf] — all static-indexed
    const int NT = K >> 6;

    // vmcnt ledger (validated round 10): entering tile kt, 4 loads outstanding
    // ({B1,A1}@cur from P3/P4 of kt-1). P1 stages +2 -> vmcnt(4) retires B1@cur;
    // P2 stages +2 -> vmcnt(4) retires A1@cur; P4 stages +2 (8 out) -> vmcnt(4)
    // retires {A0',B0'}. Last tile stages nothing: P1 drains vmcnt(0).
    for (int kt = 0; kt < NT; ++kt) {
        const int cur = kt & 1;
        _Float16* cb = smem + cur * 32768;
        _Float16* nb = smem + (cur ^ 1) * 32768;
        const _Float16* cA0 = cb;
        const _Float16* cA1 = cb + 8192;
        const _Float16* cB0 = cb + 16384;
        const _Float16* cB1 = cb + 24576;
        const int k1 = (kt + 1) << 6;
        const bool more = (kt + 1 < NT);

        half8 af[4][2], bf0[2][2], bf1[2][2];

        // Phase 1: quadrant (0,0) = A0 x B0. Both guaranteed by prev P4.
        READ_AF(cA0);
        READ_BF(bf0, cB0);
        if (more) stage_half(A, K, bm, k1, nb, t);             // A0'
        PHASE_CORE(acc[0][0], bf0);
        if (more) { asm volatile("s_waitcnt vmcnt(4)" ::: "memory"); }  // retires B1@cur
        else      { asm volatile("s_waitcnt vmcnt(0)" ::: "memory"); }  // drain {B1,A1}@cur
        END_BARRIER();

        // Phase 2: quadrant (0,1) = A0 x B1. Read B1 into bf1 (bf0 retained).
        READ_BF(bf1, cB1);
        if (more) stage_half(B, K, bn, k1, nb + 16384, t);     // B0'
        PHASE_CORE(acc[0][1], bf1);
        if (more) { asm volatile("s_waitcnt vmcnt(4)" ::: "memory"); }  // retires A1@cur
        END_BARRIER();

        // Phase 3: quadrant (1,1) = A1 x B1. Read A1 (af overwritten; bf1 reused).
        READ_AF(cA1);
        if (more) stage_half(B, K, bn + 128, k1, nb + 24576, t); // B1'
        PHASE_CORE(acc[1][1], bf1);
        END_BARRIER();

        // Phase 4: quadrant (1,0) = A1 x B0. ZERO ds_reads (af=A1, bf0 retained).
        if (more) stage_half(A, K, bm + 128, k1, nb + 8192, t);  // A1'
        PHASE_CORE(acc[1][0], bf0);
        if (more) { asm volatile("s_waitcnt vmcnt(4)" ::: "memory"); }  // retires A0',B0'
        END_BARRIER();
    }

    // Epilogue: C/D layout col=lane&15, row=(lane>>4)*4+reg (validated)
    #pragma unroll
    for (int qm = 0; qm < 2; ++qm)
      #pragma unroll
      for (int qn = 0; qn < 2; ++qn)
        #pragma unroll
        for (int nf = 0; nf < 2; ++nf) {
            const int gcol = bn + qn * 128 + wcol * 32 + nf * 16 + (lane & 15);
            const float bq = qfix(bias[gcol]);
            #pragma unroll
            for (int mf = 0; mf < 4; ++mf) {
                const int grow = bm + qm * 128 + wrow * 64 + mf * 16 + ((lane >> 4) << 2);
                float* p = C + (size_t)grow * N + gcol;
                #pragma unroll
                for (int r = 0; r < 4; ++r)
                    p[(size_t)r * N] = acc[qm][qn][mf][nf][r] + bq;
            }
        }
}

extern "C" void kernel_launch(void* const* d_in, const int* in_sizes, int n_in,
                              void* d_out, int out_size, void* d_ws, size_t ws_size,
                              hipStream_t stream) {
    const float* x     = (const float*)d_in[0];
    const float* shift = (const float*)d_in[1];
    const float* sign  = (const float*)d_in[2];
    const float* bias  = (const float*)d_in[3];
    float* out = (float*)d_out;

    const int N = in_sizes[3];            // 4096
    const int K = in_sizes[1] / N;        // 4096
    const int M = in_sizes[0] / K;        // 8192

    _Float16* xq = (_Float16*)d_ws;
    _Float16* v  = (_Float16*)((char*)d_ws + (size_t)M * K * sizeof(_Float16));

    quantize_x_kernel<<<2048, 256, 0, stream>>>(x, xq, M * K / 4);
    make_v_kernel<<<2048, 256, 0, stream>>>(shift, sign, v, N * K / 4);

    (void)hipFuncSetAttribute(reinterpret_cast<const void*>(gemm8_kernel),
                              hipFuncAttributeMaxDynamicSharedMemorySize, 131072);
    const int nblk = (M / 256) * (N / 256);
    gemm8_kernel<<<nblk, 512, 131072, stream>>>(xq, v, bias, out, M, N, K);
}